// Round 6
// baseline (12085.684 us; speedup 1.0000x reference)
//
#include <hip/hip_runtime.h>
#include <math.h>

namespace {
constexpr int   Bb    = 16;
constexpr int   Nn    = 2048;
constexpr int   Mm    = 2048;
constexpr float EPSf  = 0.005f;
constexpr float TOLf  = 1e-3f;
constexpr int   MAXIT = 100;
constexpr float LN2f  = 0.69314718055994531f;
constexpr float C2f   = 288.53900817779268f;   // log2(e)/EPS
constexpr int   BLOCK = 256;
constexpr int   SUBS  = 64;                    // blocks per batch
constexpr int   RPB   = Nn / SUBS;             // rows per block = 32
constexpr int   GRID  = Bb * SUBS;             // 1024
constexpr int   RW    = 8;                     // rows per wave (in registers)
}

__device__ __forceinline__ float ex2(float x) { return __builtin_amdgcn_exp2f(x); }

__device__ __forceinline__ void stage(const float* __restrict__ pts,
                                      const float* __restrict__ pot,
                                      float4* lds, int tid) {
  for (int i = tid; i < Mm; i += BLOCK) {
    float x = pts[3 * i + 0];
    float y = pts[3 * i + 1];
    float z = pts[3 * i + 2];
    lds[i] = make_float4(x, y, z, pot[i] * C2f);
  }
}

__global__ __launch_bounds__(BLOCK) void init_ws(unsigned* w, int nwords) {
  int i = blockIdx.x * BLOCK + threadIdx.x;
  if (i < nwords) w[i] = 0u;
}

// One Sinkhorn half-step. Each wave holds RW=8 query rows in registers and
// scans the staged cloud once, 8 points per group (8 ds_read_b128 issued
// back-to-back for latency overlap). launch_bounds(.,2): 256-VGPR cap so the
// compiler keeps all state in arch VGPRs (no AGPR shuffle tax seen in R5).
__global__ __launch_bounds__(BLOCK, 2) void sink_pass(
    const float* __restrict__ prows, const float* __restrict__ pcols,
    const float* __restrict__ potc, float* __restrict__ potr,
    unsigned* slot, const unsigned* chku, const unsigned* chkv) {
  if (chku != nullptr) {
    if (__uint_as_float(*chku) < TOLf && __uint_as_float(*chkv) < TOLf) return;
  }
  __shared__ float4 lds[Mm];                    // 32 KB
  const int tid = threadIdx.x, lane = tid & 63, wid = tid >> 6;
  const int b = blockIdx.x >> 6, sub = blockIdx.x & 63;
  const float* PR = prows + b * Nn * 3;
  const float* PC = pcols + b * Mm * 3;

  stage(PC, potc + b * Mm, lds, tid);
  __syncthreads();

  const int base_n = sub * RPB + wid * RW;
  float qx[RW], qy[RW], qz[RW], q1[RW], rm[RW], ss[RW];
  #pragma unroll
  for (int r = 0; r < RW; ++r) {
    int n = base_n + r;
    qx[r] = PR[3 * n]; qy[r] = PR[3 * n + 1]; qz[r] = PR[3 * n + 2];
    q1[r] = fmaf(qz[r], qz[r], fmaf(qy[r], qy[r], qx[r] * qx[r]));
    rm[r] = -3.0e38f; ss[r] = 0.0f;
  }

  const float4* p = lds + lane;
  for (int j = 0; j < 32; j += 8) {             // 4 iterations, 8 points each
    float4 f[8];
    #pragma unroll
    for (int k = 0; k < 8; ++k) f[k] = p[(j + k) * 64];
    float sq[8];
    #pragma unroll
    for (int k = 0; k < 8; ++k)
      sq[k] = fmaf(f[k].z, f[k].z, fmaf(f[k].y, f[k].y, f[k].x * f[k].x));
    #pragma unroll
    for (int r = 0; r < RW; ++r) {
      float y[8];
      #pragma unroll
      for (int k = 0; k < 8; ++k) {
        float dot = fmaf(f[k].z, qz[r], fmaf(f[k].y, qy[r], f[k].x * qx[r]));
        float d2  = fmaxf(fmaf(-2.0f, dot, q1[r] + sq[k]), 0.0f);
        y[k] = fmaf(__builtin_amdgcn_sqrtf(d2), -C2f, f[k].w);
      }
      float pm = fmaxf(fmaxf(fmaxf(y[0], y[1]), fmaxf(y[2], y[3])),
                       fmaxf(fmaxf(y[4], y[5]), fmaxf(y[6], y[7])));
      float nm = fmaxf(rm[r], pm);
      float e  = (ex2(y[0] - nm) + ex2(y[1] - nm)) + (ex2(y[2] - nm) + ex2(y[3] - nm))
               + (ex2(y[4] - nm) + ex2(y[5] - nm)) + (ex2(y[6] - nm) + ex2(y[7] - nm));
      ss[r] = fmaf(ss[r], ex2(rm[r] - nm), e);
      rm[r] = nm;
    }
  }

  const float log_ab = logf(1.0f / 2048.0f + 1e-8f);
  float* QR = potr + b * Nn;
  float dmax = 0.0f;
  #pragma unroll
  for (int r = 0; r < RW; ++r) {
    // two-phase merge: max-reduce, single rescale exp2, sum-reduce
    float gm = rm[r];
    #pragma unroll
    for (int off = 1; off < 64; off <<= 1) gm = fmaxf(gm, __shfl_xor(gm, off));
    float sc = ss[r] * ex2(rm[r] - gm);
    #pragma unroll
    for (int off = 1; off < 64; off <<= 1) sc += __shfl_xor(sc, off);
    float lse = (gm + __builtin_amdgcn_logf(sc)) * LN2f;   // v_log_f32 is log2
    float pnew = EPSf * (log_ab - lse);
    if (lane == 0) {
      int n = base_n + r;
      dmax = fmaxf(dmax, fabsf(pnew - QR[n]));
      QR[n] = pnew;
    }
  }
  if (lane == 0) atomicMax(slot, __float_as_uint(dmax));
}

// emd_total += sum_{n,m} exp((u+v-dist)/eps) * dist
__global__ __launch_bounds__(BLOCK, 2) void final_emd(
    const float* __restrict__ p1, const float* __restrict__ p2,
    const float* __restrict__ U, const float* __restrict__ V, double* etot) {
  __shared__ float4 lds[Mm];
  const int tid = threadIdx.x, lane = tid & 63, wid = tid >> 6;
  const int b = blockIdx.x >> 6, sub = blockIdx.x & 63;
  const float* P1 = p1 + b * Nn * 3;

  stage(p2 + b * Mm * 3, V + b * Mm, lds, tid);
  __syncthreads();

  const int base_n = sub * RPB + wid * RW;
  float qx[RW], qy[RW], qz[RW], q1[RW], uc[RW], ac[RW];
  #pragma unroll
  for (int r = 0; r < RW; ++r) {
    int n = base_n + r;
    qx[r] = P1[3 * n]; qy[r] = P1[3 * n + 1]; qz[r] = P1[3 * n + 2];
    q1[r] = fmaf(qz[r], qz[r], fmaf(qy[r], qy[r], qx[r] * qx[r]));
    uc[r] = U[b * Nn + n] * C2f;
    ac[r] = 0.0f;
  }

  const float4* p = lds + lane;
  for (int j = 0; j < 32; j += 8) {
    float4 f[8];
    #pragma unroll
    for (int k = 0; k < 8; ++k) f[k] = p[(j + k) * 64];
    float sq[8];
    #pragma unroll
    for (int k = 0; k < 8; ++k)
      sq[k] = fmaf(f[k].z, f[k].z, fmaf(f[k].y, f[k].y, f[k].x * f[k].x));
    #pragma unroll
    for (int r = 0; r < RW; ++r) {
      #pragma unroll
      for (int k = 0; k < 8; ++k) {
        float dot = fmaf(f[k].z, qz[r], fmaf(f[k].y, qy[r], f[k].x * qx[r]));
        float d2  = fmaxf(fmaf(-2.0f, dot, q1[r] + sq[k]), 0.0f);
        float dist = __builtin_amdgcn_sqrtf(d2);
        float y2 = fmaf(dist, -C2f, f[k].w) + uc[r];
        ac[r] = fmaf(ex2(y2), dist, ac[r]);
      }
    }
  }
  float acc = 0.0f;
  #pragma unroll
  for (int r = 0; r < RW; ++r) acc += ac[r];
  #pragma unroll
  for (int off = 1; off < 64; off <<= 1) acc += __shfl_xor(acc, off);
  if (lane == 0) atomicAdd(etot, (double)acc);
}

__global__ void write_out(const double* etot, float* out) {
  out[0] = (float)(*etot / (double)Bb);
}

extern "C" void kernel_launch(void* const* d_in, const int* in_sizes, int n_in,
                              void* d_out, int out_size, void* d_ws, size_t ws_size,
                              hipStream_t stream) {
  (void)in_sizes; (void)n_in; (void)out_size; (void)ws_size;
  const float* p1 = (const float*)d_in[0];
  const float* p2 = (const float*)d_in[1];
  char* ws = (char*)d_ws;
  float*    U     = (float*)(ws + 0);           // 16*2048 f32
  float*    V     = (float*)(ws + 131072);      // 16*2048 f32
  unsigned* maxdu = (unsigned*)(ws + 262144);   // 100 slots
  unsigned* maxdv = (unsigned*)(ws + 262544);   // 100 slots
  double*   etot  = (double*)(ws + 262944);     // 8-aligned

  const int nwords = 2 * Bb * Nn + 2 * MAXIT + 2;   // U,V + slots + etot
  init_ws<<<(nwords + BLOCK - 1) / BLOCK, BLOCK, 0, stream>>>((unsigned*)ws, nwords);

  for (int it = 0; it < MAXIT; ++it) {
    const unsigned* cu = it ? (maxdu + it - 1) : nullptr;
    const unsigned* cv = it ? (maxdv + it - 1) : nullptr;
    // u-update: rows = p1, staged = (p2, V), writes U
    sink_pass<<<GRID, BLOCK, 0, stream>>>(p1, p2, V, U, maxdu + it, cu, cv);
    // v-update: rows = p2, staged = (p1, U_new), writes V
    sink_pass<<<GRID, BLOCK, 0, stream>>>(p2, p1, U, V, maxdv + it, cu, cv);
  }

  final_emd<<<GRID, BLOCK, 0, stream>>>(p1, p2, U, V, etot);
  write_out<<<1, 1, 0, stream>>>(etot, (float*)d_out);
}

// Round 7
// 6760.572 us; speedup vs baseline: 1.7877x; 1.7877x over previous
//
#include <hip/hip_runtime.h>
#include <math.h>

namespace {
constexpr int   Bb    = 16;
constexpr int   Nn    = 2048;
constexpr int   Mm    = 2048;
constexpr float EPSf  = 0.005f;
constexpr float TOLf  = 1e-3f;
constexpr int   MAXIT = 100;
constexpr float LN2f  = 0.69314718055994531f;
constexpr float C2f   = 288.53900817779268f;   // log2(e)/EPS
constexpr int   BLOCK = 256;
constexpr int   SUBS  = 64;                    // blocks per batch
constexpr int   RPB   = Nn / SUBS;             // rows per block = 32
constexpr int   GRID  = Bb * SUBS;             // 1024
constexpr int   RW    = 8;                     // rows per wave (in registers)
constexpr int   SLOTSTRIDE = 16;               // dwords per (it,batch) slot line (64B)
}

__device__ __forceinline__ float ex2(float x) { return __builtin_amdgcn_exp2f(x); }

__device__ __forceinline__ void stage(const float* __restrict__ pts,
                                      const float* __restrict__ pot,
                                      float4* lds, int tid) {
  for (int i = tid; i < Mm; i += BLOCK) {
    float x = pts[3 * i + 0];
    float y = pts[3 * i + 1];
    float z = pts[3 * i + 2];
    lds[i] = make_float4(x, y, z, pot[i] * C2f);
  }
}

__global__ __launch_bounds__(BLOCK) void init_ws(unsigned* w, int nwords) {
  int i = blockIdx.x * BLOCK + threadIdx.x;
  if (i < nwords) w[i] = 0u;
}

// One Sinkhorn half-step. RW=8 rows/wave in registers, 8-point LDS groups.
// Convergence: per-block dmax -> ONE atomicMax per block into a per-batch
// 64B-padded slot (64 blocks/address, 16 addresses) instead of 4096 waves
// hammering one dword (R2-R6: invariant 65us = serialized atomic tail).
// Freeze: frozen iters never write their slots (stay 0 < TOL) -> sticky.
__global__ __launch_bounds__(BLOCK, 2) void sink_pass(
    const float* __restrict__ prows, const float* __restrict__ pcols,
    const float* __restrict__ potc, float* __restrict__ potr,
    unsigned* slotbase, const unsigned* chk, int uvsel) {
  if (chk != nullptr) {
    float m = 0.0f;
    #pragma unroll
    for (int i = 0; i < Bb; ++i) {
      unsigned a = __hip_atomic_load(chk + i * SLOTSTRIDE + 0, __ATOMIC_RELAXED, __HIP_MEMORY_SCOPE_AGENT);
      unsigned c = __hip_atomic_load(chk + i * SLOTSTRIDE + 1, __ATOMIC_RELAXED, __HIP_MEMORY_SCOPE_AGENT);
      m = fmaxf(m, fmaxf(__uint_as_float(a), __uint_as_float(c)));
    }
    if (m < TOLf) return;                       // converged: freeze (uniform)
  }
  __shared__ float4 lds[Mm];                    // 32 KB
  __shared__ float red[4];
  const int tid = threadIdx.x, lane = tid & 63, wid = tid >> 6;
  const int b = blockIdx.x >> 6, sub = blockIdx.x & 63;
  const float* PR = prows + b * Nn * 3;
  const float* PC = pcols + b * Mm * 3;

  stage(PC, potc + b * Mm, lds, tid);
  __syncthreads();

  const int base_n = sub * RPB + wid * RW;
  float qx[RW], qy[RW], qz[RW], q1[RW], rm[RW], ss[RW];
  #pragma unroll
  for (int r = 0; r < RW; ++r) {
    int n = base_n + r;
    qx[r] = PR[3 * n]; qy[r] = PR[3 * n + 1]; qz[r] = PR[3 * n + 2];
    q1[r] = fmaf(qz[r], qz[r], fmaf(qy[r], qy[r], qx[r] * qx[r]));
    rm[r] = -3.0e38f; ss[r] = 0.0f;
  }

  const float4* p = lds + lane;
  for (int j = 0; j < 32; j += 8) {             // 4 iterations, 8 points each
    float4 f[8];
    #pragma unroll
    for (int k = 0; k < 8; ++k) f[k] = p[(j + k) * 64];
    float sq[8];
    #pragma unroll
    for (int k = 0; k < 8; ++k)
      sq[k] = fmaf(f[k].z, f[k].z, fmaf(f[k].y, f[k].y, f[k].x * f[k].x));
    #pragma unroll
    for (int r = 0; r < RW; ++r) {
      float y[8];
      #pragma unroll
      for (int k = 0; k < 8; ++k) {
        float dot = fmaf(f[k].z, qz[r], fmaf(f[k].y, qy[r], f[k].x * qx[r]));
        float d2  = fmaxf(fmaf(-2.0f, dot, q1[r] + sq[k]), 0.0f);
        y[k] = fmaf(__builtin_amdgcn_sqrtf(d2), -C2f, f[k].w);
      }
      float pm = fmaxf(fmaxf(fmaxf(y[0], y[1]), fmaxf(y[2], y[3])),
                       fmaxf(fmaxf(y[4], y[5]), fmaxf(y[6], y[7])));
      float nm = fmaxf(rm[r], pm);
      float e  = (ex2(y[0] - nm) + ex2(y[1] - nm)) + (ex2(y[2] - nm) + ex2(y[3] - nm))
               + (ex2(y[4] - nm) + ex2(y[5] - nm)) + (ex2(y[6] - nm) + ex2(y[7] - nm));
      ss[r] = fmaf(ss[r], ex2(rm[r] - nm), e);
      rm[r] = nm;
    }
  }

  const float log_ab = logf(1.0f / 2048.0f + 1e-8f);
  float* QR = potr + b * Nn;
  float dmax = 0.0f;
  #pragma unroll
  for (int r = 0; r < RW; ++r) {
    // two-phase merge: max-reduce, single rescale exp2, sum-reduce
    float gm = rm[r];
    #pragma unroll
    for (int off = 1; off < 64; off <<= 1) gm = fmaxf(gm, __shfl_xor(gm, off));
    float sc = ss[r] * ex2(rm[r] - gm);
    #pragma unroll
    for (int off = 1; off < 64; off <<= 1) sc += __shfl_xor(sc, off);
    float lse = (gm + __builtin_amdgcn_logf(sc)) * LN2f;   // v_log_f32 is log2
    float pnew = EPSf * (log_ab - lse);
    if (lane == 0) {
      int n = base_n + r;
      dmax = fmaxf(dmax, fabsf(pnew - QR[n]));
      QR[n] = pnew;
    }
  }
  if (lane == 0) red[wid] = dmax;
  __syncthreads();
  if (tid == 0) {
    float m = fmaxf(fmaxf(red[0], red[1]), fmaxf(red[2], red[3]));
    atomicMax(slotbase + b * SLOTSTRIDE + uvsel, __float_as_uint(m));
  }
}

// part[blk] = block-partial of sum_{n,m} exp((u+v-dist)/eps) * dist
__global__ __launch_bounds__(BLOCK, 2) void final_emd(
    const float* __restrict__ p1, const float* __restrict__ p2,
    const float* __restrict__ U, const float* __restrict__ V,
    float* __restrict__ part) {
  __shared__ float4 lds[Mm];
  __shared__ float red[4];
  const int tid = threadIdx.x, lane = tid & 63, wid = tid >> 6;
  const int b = blockIdx.x >> 6, sub = blockIdx.x & 63;
  const float* P1 = p1 + b * Nn * 3;

  stage(p2 + b * Mm * 3, V + b * Mm, lds, tid);
  __syncthreads();

  const int base_n = sub * RPB + wid * RW;
  float qx[RW], qy[RW], qz[RW], q1[RW], uc[RW], ac[RW];
  #pragma unroll
  for (int r = 0; r < RW; ++r) {
    int n = base_n + r;
    qx[r] = P1[3 * n]; qy[r] = P1[3 * n + 1]; qz[r] = P1[3 * n + 2];
    q1[r] = fmaf(qz[r], qz[r], fmaf(qy[r], qy[r], qx[r] * qx[r]));
    uc[r] = U[b * Nn + n] * C2f;
    ac[r] = 0.0f;
  }

  const float4* p = lds + lane;
  for (int j = 0; j < 32; j += 8) {
    float4 f[8];
    #pragma unroll
    for (int k = 0; k < 8; ++k) f[k] = p[(j + k) * 64];
    float sq[8];
    #pragma unroll
    for (int k = 0; k < 8; ++k)
      sq[k] = fmaf(f[k].z, f[k].z, fmaf(f[k].y, f[k].y, f[k].x * f[k].x));
    #pragma unroll
    for (int r = 0; r < RW; ++r) {
      #pragma unroll
      for (int k = 0; k < 8; ++k) {
        float dot = fmaf(f[k].z, qz[r], fmaf(f[k].y, qy[r], f[k].x * qx[r]));
        float d2  = fmaxf(fmaf(-2.0f, dot, q1[r] + sq[k]), 0.0f);
        float dist = __builtin_amdgcn_sqrtf(d2);
        float y2 = fmaf(dist, -C2f, f[k].w) + uc[r];
        ac[r] = fmaf(ex2(y2), dist, ac[r]);
      }
    }
  }
  float acc = 0.0f;
  #pragma unroll
  for (int r = 0; r < RW; ++r) acc += ac[r];
  #pragma unroll
  for (int off = 1; off < 64; off <<= 1) acc += __shfl_xor(acc, off);
  if (lane == 0) red[wid] = acc;
  __syncthreads();
  if (tid == 0) part[blockIdx.x] = (red[0] + red[1]) + (red[2] + red[3]);
}

__global__ __launch_bounds__(BLOCK) void write_out(const float* __restrict__ part,
                                                   float* __restrict__ out) {
  __shared__ double sd[BLOCK];
  int t = threadIdx.x;
  double s = 0.0;
  for (int i = t; i < GRID; i += BLOCK) s += (double)part[i];
  sd[t] = s;
  __syncthreads();
  for (int k = BLOCK / 2; k > 0; k >>= 1) {
    if (t < k) sd[t] += sd[t + k];
    __syncthreads();
  }
  if (t == 0) out[0] = (float)(sd[0] / (double)Bb);
}

extern "C" void kernel_launch(void* const* d_in, const int* in_sizes, int n_in,
                              void* d_out, int out_size, void* d_ws, size_t ws_size,
                              hipStream_t stream) {
  (void)in_sizes; (void)n_in; (void)out_size; (void)ws_size;
  const float* p1 = (const float*)d_in[0];
  const float* p2 = (const float*)d_in[1];
  char* ws = (char*)d_ws;
  float*    U     = (float*)(ws + 0);           // 16*2048 f32  (131072 B)
  float*    V     = (float*)(ws + 131072);      // 16*2048 f32  (131072 B)
  unsigned* slots = (unsigned*)(ws + 262144);   // 100 it * 16 b * 64 B = 102400 B
  float*    part  = (float*)(ws + 364544);      // 1024 f32     (4096 B)

  // zero U, V, slots (part is overwritten unconditionally)
  const int nwords = 2 * Bb * Nn + MAXIT * Bb * SLOTSTRIDE;
  init_ws<<<(nwords + BLOCK - 1) / BLOCK, BLOCK, 0, stream>>>((unsigned*)ws, nwords);

  for (int it = 0; it < MAXIT; ++it) {
    unsigned*       sl  = slots + it * Bb * SLOTSTRIDE;
    const unsigned* chk = it ? slots + (it - 1) * Bb * SLOTSTRIDE : nullptr;
    // u-update: rows = p1, staged = (p2, V), writes U  -> slot dword 0
    sink_pass<<<GRID, BLOCK, 0, stream>>>(p1, p2, V, U, sl, chk, 0);
    // v-update: rows = p2, staged = (p1, U_new), writes V -> slot dword 1
    sink_pass<<<GRID, BLOCK, 0, stream>>>(p2, p1, U, V, sl, chk, 1);
  }

  final_emd<<<GRID, BLOCK, 0, stream>>>(p1, p2, U, V, part);
  write_out<<<1, BLOCK, 0, stream>>>(part, (float*)d_out);
}

// Round 8
// 6064.013 us; speedup vs baseline: 1.9930x; 1.1149x over previous
//
#include <hip/hip_runtime.h>
#include <math.h>

namespace {
constexpr int   Bb    = 16;
constexpr int   Nn    = 2048;
constexpr int   Mm    = 2048;
constexpr float EPSf  = 0.005f;
constexpr float TOLf  = 1e-3f;
constexpr int   MAXIT = 100;
constexpr float LN2f  = 0.69314718055994531f;
constexpr float C2f   = 288.53900817779268f;   // log2(e)/EPS
constexpr int   BLOCK = 256;
constexpr int   RW    = 4;                     // rows per wave (registers)
constexpr int   RPB   = 16;                    // rows per block (4 waves * RW)
constexpr int   SUBS  = Nn / RPB;              // 128 blocks per batch
constexpr int   GRID  = Bb * SUBS;             // 2048
constexpr int   SLOTSTRIDE = 16;               // dwords per (it,batch) slot line
}

__device__ __forceinline__ float ex2(float x) { return __builtin_amdgcn_exp2f(x); }

// one-time: [B][N][3] scalar coords -> [B][N] float4 (x,y,z, pot*C2f=0)
__global__ __launch_bounds__(BLOCK) void pack_pts(const float* __restrict__ p,
                                                  float4* __restrict__ pk, int npts) {
  int i = blockIdx.x * BLOCK + threadIdx.x;
  if (i < npts) pk[i] = make_float4(p[3 * i], p[3 * i + 1], p[3 * i + 2], 0.0f);
}

__global__ __launch_bounds__(BLOCK) void init_ws(unsigned* w, int nwords) {
  int i = blockIdx.x * BLOCK + threadIdx.x;
  if (i < nwords) w[i] = 0u;
}

// One Sinkhorn half-step, LDS-free: the 32KB column cloud is L1/L2-resident;
// potentials ride fused in .w (written by the producing pass). RW=4 rows/wave,
// diff-form distance, launch_bounds(...,8) targets <=64 VGPR = 8 waves/SIMD.
// Freeze: frozen iters never write slots (stay 0 < TOL) -> sticky (as R7).
__global__ __launch_bounds__(BLOCK, 8) void sink_pass(
    const float4* __restrict__ pkc,   // column cloud, pot*C2f fused in .w
    float4* __restrict__ pkr,         // row cloud; we write .w = pnew*C2f
    float* __restrict__ potr,         // plain potential array (deltas + final)
    unsigned* slotbase, const unsigned* chk, int uvsel) {
  if (chk != nullptr) {
    float m = 0.0f;
    #pragma unroll
    for (int i = 0; i < Bb; ++i) {
      unsigned a = __hip_atomic_load(chk + i * SLOTSTRIDE + 0, __ATOMIC_RELAXED, __HIP_MEMORY_SCOPE_AGENT);
      unsigned c = __hip_atomic_load(chk + i * SLOTSTRIDE + 1, __ATOMIC_RELAXED, __HIP_MEMORY_SCOPE_AGENT);
      m = fmaxf(m, fmaxf(__uint_as_float(a), __uint_as_float(c)));
    }
    if (m < TOLf) return;                       // converged: freeze (uniform)
  }
  __shared__ float red[4];
  const int tid = threadIdx.x, lane = tid & 63, wid = tid >> 6;
  const int b = blockIdx.x >> 7, sub = blockIdx.x & 127;
  const float4* PC = pkc + b * Mm;
  float4*       PRq = pkr + b * Nn;
  float*        QR  = potr + b * Nn;

  const int base_n = sub * RPB + wid * RW;
  float qx[RW], qy[RW], qz[RW], rm[RW], ss[RW];
  #pragma unroll
  for (int r = 0; r < RW; ++r) {
    float4 q = PRq[base_n + r];                 // same addr across wave: broadcast
    qx[r] = q.x; qy[r] = q.y; qz[r] = q.z;
    rm[r] = -3.0e38f; ss[r] = 0.0f;
  }

  const float4* p = PC + lane;
  for (int j = 0; j < 32; j += 4) {             // 8 iterations, 4 points each
    float4 f0 = p[(j + 0) * 64];
    float4 f1 = p[(j + 1) * 64];
    float4 f2 = p[(j + 2) * 64];
    float4 f3 = p[(j + 3) * 64];
    #pragma unroll
    for (int r = 0; r < RW; ++r) {
      float dx0 = f0.x - qx[r], dy0 = f0.y - qy[r], dz0 = f0.z - qz[r];
      float dx1 = f1.x - qx[r], dy1 = f1.y - qy[r], dz1 = f1.z - qz[r];
      float dx2 = f2.x - qx[r], dy2 = f2.y - qy[r], dz2 = f2.z - qz[r];
      float dx3 = f3.x - qx[r], dy3 = f3.y - qy[r], dz3 = f3.z - qz[r];
      float d0 = fmaf(dz0, dz0, fmaf(dy0, dy0, dx0 * dx0));
      float d1 = fmaf(dz1, dz1, fmaf(dy1, dy1, dx1 * dx1));
      float d2 = fmaf(dz2, dz2, fmaf(dy2, dy2, dx2 * dx2));
      float d3 = fmaf(dz3, dz3, fmaf(dy3, dy3, dx3 * dx3));
      float y0 = fmaf(__builtin_amdgcn_sqrtf(d0), -C2f, f0.w);
      float y1 = fmaf(__builtin_amdgcn_sqrtf(d1), -C2f, f1.w);
      float y2 = fmaf(__builtin_amdgcn_sqrtf(d2), -C2f, f2.w);
      float y3 = fmaf(__builtin_amdgcn_sqrtf(d3), -C2f, f3.w);
      float pm = fmaxf(fmaxf(y0, y1), fmaxf(y2, y3));
      float nm = fmaxf(rm[r], pm);
      float e  = (ex2(y0 - nm) + ex2(y1 - nm)) + (ex2(y2 - nm) + ex2(y3 - nm));
      ss[r] = fmaf(ss[r], ex2(rm[r] - nm), e);
      rm[r] = nm;
    }
  }

  const float log_ab = logf(1.0f / 2048.0f + 1e-8f);
  float* PRw = (float*)(PRq);
  float dmax = 0.0f;
  #pragma unroll
  for (int r = 0; r < RW; ++r) {
    // two-phase merge: max-reduce, single rescale exp2, sum-reduce
    float gm = rm[r];
    #pragma unroll
    for (int off = 1; off < 64; off <<= 1) gm = fmaxf(gm, __shfl_xor(gm, off));
    float sc = ss[r] * ex2(rm[r] - gm);
    #pragma unroll
    for (int off = 1; off < 64; off <<= 1) sc += __shfl_xor(sc, off);
    float lse = (gm + __builtin_amdgcn_logf(sc)) * LN2f;   // v_log_f32 is log2
    float pnew = EPSf * (log_ab - lse);
    if (lane == 0) {
      int n = base_n + r;
      dmax = fmaxf(dmax, fabsf(pnew - QR[n]));
      QR[n] = pnew;
      PRw[4 * n + 3] = pnew * C2f;              // fuse pot for consumer pass
    }
  }
  if (lane == 0) red[wid] = dmax;
  __syncthreads();
  if (tid == 0) {
    float m = fmaxf(fmaxf(red[0], red[1]), fmaxf(red[2], red[3]));
    atomicMax(slotbase + b * SLOTSTRIDE + uvsel, __float_as_uint(m));
  }
}

// part[blk] = block-partial of sum_{n,m} exp((u+v-dist)/eps) * dist
__global__ __launch_bounds__(BLOCK, 8) void final_emd(
    const float4* __restrict__ pk1,   // row cloud coords (w ignored)
    const float4* __restrict__ pk2,   // column cloud, V*C2f fused in .w
    const float* __restrict__ U, float* __restrict__ part) {
  __shared__ float red[4];
  const int tid = threadIdx.x, lane = tid & 63, wid = tid >> 6;
  const int b = blockIdx.x >> 7, sub = blockIdx.x & 127;
  const float4* PC = pk2 + b * Mm;
  const float4* PRq = pk1 + b * Nn;

  const int base_n = sub * RPB + wid * RW;
  float qx[RW], qy[RW], qz[RW], uc[RW], ac[RW];
  #pragma unroll
  for (int r = 0; r < RW; ++r) {
    float4 q = PRq[base_n + r];
    qx[r] = q.x; qy[r] = q.y; qz[r] = q.z;
    uc[r] = U[b * Nn + base_n + r] * C2f;
    ac[r] = 0.0f;
  }

  const float4* p = PC + lane;
  for (int j = 0; j < 32; j += 4) {
    float4 f0 = p[(j + 0) * 64];
    float4 f1 = p[(j + 1) * 64];
    float4 f2 = p[(j + 2) * 64];
    float4 f3 = p[(j + 3) * 64];
    #pragma unroll
    for (int r = 0; r < RW; ++r) {
      float dx0 = f0.x - qx[r], dy0 = f0.y - qy[r], dz0 = f0.z - qz[r];
      float dx1 = f1.x - qx[r], dy1 = f1.y - qy[r], dz1 = f1.z - qz[r];
      float dx2 = f2.x - qx[r], dy2 = f2.y - qy[r], dz2 = f2.z - qz[r];
      float dx3 = f3.x - qx[r], dy3 = f3.y - qy[r], dz3 = f3.z - qz[r];
      float e0 = fmaf(dz0, dz0, fmaf(dy0, dy0, dx0 * dx0));
      float e1 = fmaf(dz1, dz1, fmaf(dy1, dy1, dx1 * dx1));
      float e2 = fmaf(dz2, dz2, fmaf(dy2, dy2, dx2 * dx2));
      float e3 = fmaf(dz3, dz3, fmaf(dy3, dy3, dx3 * dx3));
      float t0 = __builtin_amdgcn_sqrtf(e0);
      float t1 = __builtin_amdgcn_sqrtf(e1);
      float t2 = __builtin_amdgcn_sqrtf(e2);
      float t3 = __builtin_amdgcn_sqrtf(e3);
      ac[r] = fmaf(ex2(fmaf(t0, -C2f, f0.w) + uc[r]), t0, ac[r]);
      ac[r] = fmaf(ex2(fmaf(t1, -C2f, f1.w) + uc[r]), t1, ac[r]);
      ac[r] = fmaf(ex2(fmaf(t2, -C2f, f2.w) + uc[r]), t2, ac[r]);
      ac[r] = fmaf(ex2(fmaf(t3, -C2f, f3.w) + uc[r]), t3, ac[r]);
    }
  }
  float acc = 0.0f;
  #pragma unroll
  for (int r = 0; r < RW; ++r) acc += ac[r];
  #pragma unroll
  for (int off = 1; off < 64; off <<= 1) acc += __shfl_xor(acc, off);
  if (lane == 0) red[wid] = acc;
  __syncthreads();
  if (tid == 0) part[blockIdx.x] = (red[0] + red[1]) + (red[2] + red[3]);
}

__global__ __launch_bounds__(BLOCK) void write_out(const float* __restrict__ part,
                                                   float* __restrict__ out) {
  __shared__ double sd[BLOCK];
  int t = threadIdx.x;
  double s = 0.0;
  for (int i = t; i < GRID; i += BLOCK) s += (double)part[i];
  sd[t] = s;
  __syncthreads();
  for (int k = BLOCK / 2; k > 0; k >>= 1) {
    if (t < k) sd[t] += sd[t + k];
    __syncthreads();
  }
  if (t == 0) out[0] = (float)(sd[0] / (double)Bb);
}

extern "C" void kernel_launch(void* const* d_in, const int* in_sizes, int n_in,
                              void* d_out, int out_size, void* d_ws, size_t ws_size,
                              hipStream_t stream) {
  (void)in_sizes; (void)n_in; (void)out_size; (void)ws_size;
  const float* p1 = (const float*)d_in[0];
  const float* p2 = (const float*)d_in[1];
  char* ws = (char*)d_ws;
  float4*   pk1   = (float4*)(ws + 0);          // 16*2048*16B = 524288
  float4*   pk2   = (float4*)(ws + 524288);     // 524288
  float*    U     = (float*)(ws + 1048576);     // 131072
  float*    V     = (float*)(ws + 1179648);     // 131072
  unsigned* slots = (unsigned*)(ws + 1310720);  // 100*16*64B = 102400
  float*    part  = (float*)(ws + 1413120);     // 2048*4 = 8192

  const int npts = Bb * Nn;                     // 32768 per cloud
  pack_pts<<<(npts + BLOCK - 1) / BLOCK, BLOCK, 0, stream>>>(p1, pk1, npts);
  pack_pts<<<(npts + BLOCK - 1) / BLOCK, BLOCK, 0, stream>>>(p2, pk2, npts);
  const int nwords = (2 * Bb * Nn * 4 + MAXIT * Bb * SLOTSTRIDE * 4) / 4;
  init_ws<<<(nwords + BLOCK - 1) / BLOCK, BLOCK, 0, stream>>>((unsigned*)(ws + 1048576), nwords);

  for (int it = 0; it < MAXIT; ++it) {
    unsigned*       sl  = slots + it * Bb * SLOTSTRIDE;
    const unsigned* chk = it ? slots + (it - 1) * Bb * SLOTSTRIDE : nullptr;
    // u-update: rows = pk1, cols = pk2 (V fused), writes U + pk1.w
    sink_pass<<<GRID, BLOCK, 0, stream>>>(pk2, pk1, U, sl, chk, 0);
    // v-update: rows = pk2, cols = pk1 (U fused), writes V + pk2.w
    sink_pass<<<GRID, BLOCK, 0, stream>>>(pk1, pk2, V, sl, chk, 1);
  }

  final_emd<<<GRID, BLOCK, 0, stream>>>(pk1, pk2, U, part);
  write_out<<<1, BLOCK, 0, stream>>>(part, (float*)d_out);
}